// Round 1
// baseline (385.799 us; speedup 1.0000x reference)
//
#include <hip/hip_runtime.h>

#define EPSF 1e-20f

// Problem shape (fixed by setup_inputs): B=8, N=256, H=128
// edge_gate (B,N,N,H) fp32 = 268.4 MB  -> the one unavoidable HBM stream.

namespace {
constexpr int Bc = 8;
constexpr int Nc = 256;
constexpr int Hc = 128;
constexpr int ROWS = Bc * Nc;  // 2048
}

// ---------------------------------------------------------------------------
// Kernel 1: per row (b,n):
//   Ux[row,h] = m * (sum_k x[row,k]*Uw[h,k] + Ub[h])
//   W [row,h] = m * m * (sum_k x[row,k]*Vw[h,k] + Vb[h])
// (W = mask_j * Vx, since reference multiplies eg by mask_j and Vx already
//  carries one factor of mask_j.)
// grid = 512 blocks, 4 rows/block; block = 128 threads, lane = h.
// x loads are wave-uniform (blockIdx + loop index only) -> s_load path.
// ---------------------------------------------------------------------------
__global__ __launch_bounds__(128) void nf_prep(
    const float* __restrict__ x,     // (ROWS, H)
    const float* __restrict__ mask,  // (ROWS)
    const float* __restrict__ Uw,    // (H, H) row-major, out = x @ Uw^T
    const float* __restrict__ Ub,    // (H)
    const float* __restrict__ Vw,    // (H, H)
    const float* __restrict__ Vb,    // (H)
    float* __restrict__ Ux,          // (ROWS, H) out
    float* __restrict__ W)           // (ROWS, H) out
{
    const int h = threadIdx.x;           // 0..127
    const int row0 = blockIdx.x * 4;     // 4 rows per block

    float accu[4] = {0.f, 0.f, 0.f, 0.f};
    float accv[4] = {0.f, 0.f, 0.f, 0.f};

    const float4* uw4 = reinterpret_cast<const float4*>(Uw + (size_t)h * Hc);
    const float4* vw4 = reinterpret_cast<const float4*>(Vw + (size_t)h * Hc);

    for (int k4 = 0; k4 < Hc / 4; ++k4) {
        const float4 u = uw4[k4];
        const float4 v = vw4[k4];
#pragma unroll
        for (int r = 0; r < 4; ++r) {
            // wave-uniform address -> scalar load
            const float4 xv = *reinterpret_cast<const float4*>(
                x + (size_t)(row0 + r) * Hc + k4 * 4);
            accu[r] += xv.x * u.x + xv.y * u.y + xv.z * u.z + xv.w * u.w;
            accv[r] += xv.x * v.x + xv.y * v.y + xv.z * v.z + xv.w * v.w;
        }
    }

    const float bu = Ub[h];
    const float bv = Vb[h];
#pragma unroll
    for (int r = 0; r < 4; ++r) {
        const int row = row0 + r;
        const float m = mask[row];
        Ux[(size_t)row * Hc + h] = m * (accu[r] + bu);
        W[(size_t)row * Hc + h] = m * m * (accv[r] + bv);
    }
}

// ---------------------------------------------------------------------------
// Kernel 2: stream edge_gate once.
//   s1[b,i,h] = sum_j e[b,i,j,h] * W[b,j,h]
//   s0[b,i,h] = sum_j e[b,i,j,h] * mask[b,j]
//   out = Ux + (m_i*s1) / (EPS + m_i*s0)
// grid = 256 blocks (8 i-rows each), block = 256 threads:
//   lane c = tid&31 handles h = 4c..4c+3 (float4), group g = tid>>5 -> i.
// edge_gate reads: 512 B contiguous per (i,j) row -> fully coalesced.
// W reads: 128 KB/b working set, L2-resident (1 MB total).
// ---------------------------------------------------------------------------
__global__ __launch_bounds__(256) void nf_edge(
    const float* __restrict__ eg,    // (B, N, N, H)
    const float* __restrict__ mask,  // (B, N)
    const float* __restrict__ Ux,    // (B, N, H)
    const float* __restrict__ W,     // (B, N, H)
    float* __restrict__ out)         // (B, N, H)
{
    const int c = threadIdx.x & 31;   // h/4
    const int g = threadIdx.x >> 5;   // 0..7
    const int blocksPerB = Nc / 8;    // 32
    const int b = blockIdx.x / blocksPerB;
    const int i = (blockIdx.x % blocksPerB) * 8 + g;

    const float* __restrict__ egp =
        eg + ((size_t)(b * Nc + i) * Nc) * Hc + c * 4;
    const float* __restrict__ wp = W + (size_t)(b * Nc) * Hc + c * 4;
    const float* __restrict__ mp = mask + (size_t)b * Nc;

    float4 s1 = {0.f, 0.f, 0.f, 0.f};
    float4 s0 = {0.f, 0.f, 0.f, 0.f};

#pragma unroll 4
    for (int j = 0; j < Nc; ++j) {
        const float mj = mp[j];  // wave-uniform -> s_load, scalar cache
        const float4 e = *reinterpret_cast<const float4*>(egp + (size_t)j * Hc);
        const float4 w = *reinterpret_cast<const float4*>(wp + (size_t)j * Hc);
        s1.x += e.x * w.x;
        s1.y += e.y * w.y;
        s1.z += e.z * w.z;
        s1.w += e.w * w.w;
        s0.x += e.x * mj;
        s0.y += e.y * mj;
        s0.z += e.z * mj;
        s0.w += e.w * mj;
    }

    const float mi = mp[i];
    const size_t oidx = (size_t)(b * Nc + i) * Hc + c * 4;
    const float4 ux = *reinterpret_cast<const float4*>(Ux + oidx);

    float4 o;
    o.x = ux.x + (mi * s1.x) / (EPSF + mi * s0.x);
    o.y = ux.y + (mi * s1.y) / (EPSF + mi * s0.y);
    o.z = ux.z + (mi * s1.z) / (EPSF + mi * s0.z);
    o.w = ux.w + (mi * s1.w) / (EPSF + mi * s0.w);
    *reinterpret_cast<float4*>(out + oidx) = o;
}

extern "C" void kernel_launch(void* const* d_in, const int* in_sizes, int n_in,
                              void* d_out, int out_size, void* d_ws, size_t ws_size,
                              hipStream_t stream) {
    const float* x    = (const float*)d_in[0];  // (B,N,H)
    const float* eg   = (const float*)d_in[1];  // (B,N,N,H)
    const float* mask = (const float*)d_in[2];  // (B,N)
    const float* Uw   = (const float*)d_in[3];  // (H,H)
    const float* Ub   = (const float*)d_in[4];  // (H)
    const float* Vw   = (const float*)d_in[5];  // (H,H)
    const float* Vb   = (const float*)d_in[6];  // (H)
    float* out = (float*)d_out;

    // workspace: Ux (ROWS*H) then W (ROWS*H) floats = 2 MB total
    float* Ux = (float*)d_ws;
    float* W  = Ux + (size_t)ROWS * Hc;

    nf_prep<<<ROWS / 4, 128, 0, stream>>>(x, mask, Uw, Ub, Vw, Vb, Ux, W);
    nf_edge<<<(Bc * Nc) / 8, 256, 0, stream>>>(eg, mask, Ux, W, out);
}

// Round 2
// 382.651 us; speedup vs baseline: 1.0082x; 1.0082x over previous
//
#include <hip/hip_runtime.h>

#define EPSF 1e-20f

// Problem shape (fixed by setup_inputs): B=8, N=256, H=128
// edge_gate (B,N,N,H) fp32 = 268.4 MB -> the one unavoidable HBM stream.
// Roofline: 268 MB / 6.3 TB/s achievable ~= 43 us.

namespace {
constexpr int Bc = 8;
constexpr int Nc = 256;
constexpr int Hc = 128;
constexpr int ROWS = Bc * Nc;  // 2048
}

// ---------------------------------------------------------------------------
// Kernel 1: per row (b,n):
//   Ux[row,h] = m * (sum_k x[row,k]*Uw[h,k] + Ub[h])
//   W [row,h] = m * m * (sum_k x[row,k]*Vw[h,k] + Vb[h])
// (W = mask_j * Vx: reference multiplies eg by mask_j and Vx already carries
//  one mask_j factor.)
// ---------------------------------------------------------------------------
__global__ __launch_bounds__(128) void nf_prep(
    const float* __restrict__ x,     // (ROWS, H)
    const float* __restrict__ mask,  // (ROWS)
    const float* __restrict__ Uw,    // (H, H)
    const float* __restrict__ Ub,    // (H)
    const float* __restrict__ Vw,    // (H, H)
    const float* __restrict__ Vb,    // (H)
    float* __restrict__ Ux,          // (ROWS, H) out
    float* __restrict__ W)           // (ROWS, H) out
{
    const int h = threadIdx.x;           // 0..127
    const int row0 = blockIdx.x * 4;     // 4 rows per block

    float accu[4] = {0.f, 0.f, 0.f, 0.f};
    float accv[4] = {0.f, 0.f, 0.f, 0.f};

    const float4* uw4 = reinterpret_cast<const float4*>(Uw + (size_t)h * Hc);
    const float4* vw4 = reinterpret_cast<const float4*>(Vw + (size_t)h * Hc);

    for (int k4 = 0; k4 < Hc / 4; ++k4) {
        const float4 u = uw4[k4];
        const float4 v = vw4[k4];
#pragma unroll
        for (int r = 0; r < 4; ++r) {
            // wave-uniform address -> scalar load path
            const float4 xv = *reinterpret_cast<const float4*>(
                x + (size_t)(row0 + r) * Hc + k4 * 4);
            accu[r] += xv.x * u.x + xv.y * u.y + xv.z * u.z + xv.w * u.w;
            accv[r] += xv.x * v.x + xv.y * v.y + xv.z * v.z + xv.w * v.w;
        }
    }

    const float bu = Ub[h];
    const float bv = Vb[h];
#pragma unroll
    for (int r = 0; r < 4; ++r) {
        const int row = row0 + r;
        const float m = mask[row];
        Ux[(size_t)row * Hc + h] = m * (accu[r] + bu);
        W[(size_t)row * Hc + h] = m * m * (accv[r] + bv);
    }
}

// ---------------------------------------------------------------------------
// Kernel 2: stream edge_gate once, j-reduction split 8-way within the block.
// grid = 2048 (one block per (b,i) output row), block = 256:
//   c = tid&31 -> h/4 (float4 over H=128), g = tid>>5 -> j-subset {g, g+8, ...}
// 8 blocks/CU -> 32 waves/CU (full occupancy) for latency hiding.
// Within a wave the two halves read adjacent j rows -> each e-load is one
// contiguous 1 KB segment. W reads (1 MB total) are L2-resident.
// Partials reduced through LDS; 128 threads do the epilogue.
// ---------------------------------------------------------------------------
__global__ __launch_bounds__(256) void nf_edge(
    const float* __restrict__ eg,    // (B, N, N, H)
    const float* __restrict__ mask,  // (B, N)
    const float* __restrict__ Ux,    // (B, N, H)
    const float* __restrict__ W,     // (B, N, H)
    float* __restrict__ out)         // (B, N, H)
{
    __shared__ float red1[8][Hc];   // 4 KB
    __shared__ float red0[8][Hc];   // 4 KB
    __shared__ float mrow[Nc];      // 1 KB

    const int tid = threadIdx.x;
    const int c = tid & 31;   // h4 index
    const int g = tid >> 5;   // j group 0..7
    const int row = blockIdx.x;      // b*Nc + i
    const int b = row >> 8;
    const int i = row & (Nc - 1);

    mrow[tid] = mask[b * Nc + tid];  // tid == j
    __syncthreads();

    const float* __restrict__ egp = eg + (size_t)row * Nc * Hc + c * 4;
    const float* __restrict__ wp  = W + (size_t)b * Nc * Hc + c * 4;

    float4 s1 = {0.f, 0.f, 0.f, 0.f};
    float4 s0 = {0.f, 0.f, 0.f, 0.f};

#pragma unroll 4
    for (int jj = 0; jj < Nc / 8; ++jj) {
        const int j = jj * 8 + g;
        const float mj = mrow[j];
        const float4 e = *reinterpret_cast<const float4*>(egp + (size_t)j * Hc);
        const float4 w = *reinterpret_cast<const float4*>(wp + (size_t)j * Hc);
        s1.x += e.x * w.x;
        s1.y += e.y * w.y;
        s1.z += e.z * w.z;
        s1.w += e.w * w.w;
        s0.x += e.x * mj;
        s0.y += e.y * mj;
        s0.z += e.z * mj;
        s0.w += e.w * mj;
    }

    *reinterpret_cast<float4*>(&red1[g][c * 4]) = s1;
    *reinterpret_cast<float4*>(&red0[g][c * 4]) = s0;
    __syncthreads();

    if (tid < Hc) {
        const int h = tid;
        float a1 = 0.f, a0 = 0.f;
#pragma unroll
        for (int g2 = 0; g2 < 8; ++g2) {
            a1 += red1[g2][h];
            a0 += red0[g2][h];
        }
        const float mi = mrow[i];
        const size_t oidx = (size_t)row * Hc + h;
        out[oidx] = Ux[oidx] + (mi * a1) / (EPSF + mi * a0);
    }
}

extern "C" void kernel_launch(void* const* d_in, const int* in_sizes, int n_in,
                              void* d_out, int out_size, void* d_ws, size_t ws_size,
                              hipStream_t stream) {
    const float* x    = (const float*)d_in[0];  // (B,N,H)
    const float* eg   = (const float*)d_in[1];  // (B,N,N,H)
    const float* mask = (const float*)d_in[2];  // (B,N)
    const float* Uw   = (const float*)d_in[3];  // (H,H)
    const float* Ub   = (const float*)d_in[4];  // (H)
    const float* Vw   = (const float*)d_in[5];  // (H,H)
    const float* Vb   = (const float*)d_in[6];  // (H)
    float* out = (float*)d_out;

    // workspace: Ux (ROWS*H) then W (ROWS*H) floats = 2 MB total
    float* Ux = (float*)d_ws;
    float* W  = Ux + (size_t)ROWS * Hc;

    nf_prep<<<ROWS / 4, 128, 0, stream>>>(x, mask, Uw, Ub, Vw, Vb, Ux, W);
    nf_edge<<<ROWS, 256, 0, stream>>>(eg, mask, Ux, W, out);
}

// Round 3
// 360.062 us; speedup vs baseline: 1.0715x; 1.0627x over previous
//
#include <hip/hip_runtime.h>

#define EPSF 1e-20f

// Problem shape (fixed): B=8, N=256, H=128
// edge_gate (B,N,N,H) fp32 = 268.4 MB -> the one unavoidable HBM stream.
// Kernel roofline: 268 MB / 6.3 TB/s ~= 43 us. Measured dur_us carries a
// ~330 us harness floor (d_ws 1 GiB re-poison @160us + input restores),
// so expected metric ~= floor + kernels.

namespace {
constexpr int Bc = 8;
constexpr int Nc = 256;
constexpr int Hc = 128;
constexpr int ROWS = Bc * Nc;  // 2048
}

typedef float f4 __attribute__((ext_vector_type(4)));

// ---------------------------------------------------------------------------
// Kernel 1: per row (b,n):
//   Ux[row,h] = m * (sum_k x[row,k]*Uw[h,k] + Ub[h])
//   W [row,h] = m * m * (sum_k x[row,k]*Vw[h,k] + Vb[h])
// (W = mask_j * Vx: reference multiplies eg by mask_j and Vx already carries
//  one mask_j factor.)
// ---------------------------------------------------------------------------
__global__ __launch_bounds__(128) void nf_prep(
    const float* __restrict__ x,     // (ROWS, H)
    const float* __restrict__ mask,  // (ROWS)
    const float* __restrict__ Uw,    // (H, H)
    const float* __restrict__ Ub,    // (H)
    const float* __restrict__ Vw,    // (H, H)
    const float* __restrict__ Vb,    // (H)
    float* __restrict__ Ux,          // (ROWS, H) out
    float* __restrict__ W)           // (ROWS, H) out
{
    const int h = threadIdx.x;           // 0..127
    const int row0 = blockIdx.x * 4;     // 4 rows per block

    float accu[4] = {0.f, 0.f, 0.f, 0.f};
    float accv[4] = {0.f, 0.f, 0.f, 0.f};

    const float4* uw4 = reinterpret_cast<const float4*>(Uw + (size_t)h * Hc);
    const float4* vw4 = reinterpret_cast<const float4*>(Vw + (size_t)h * Hc);

    for (int k4 = 0; k4 < Hc / 4; ++k4) {
        const float4 u = uw4[k4];
        const float4 v = vw4[k4];
#pragma unroll
        for (int r = 0; r < 4; ++r) {
            // wave-uniform address -> scalar load path
            const float4 xv = *reinterpret_cast<const float4*>(
                x + (size_t)(row0 + r) * Hc + k4 * 4);
            accu[r] += xv.x * u.x + xv.y * u.y + xv.z * u.z + xv.w * u.w;
            accv[r] += xv.x * v.x + xv.y * v.y + xv.z * v.z + xv.w * v.w;
        }
    }

    const float bu = Ub[h];
    const float bv = Vb[h];
#pragma unroll
    for (int r = 0; r < 4; ++r) {
        const int row = row0 + r;
        const float m = mask[row];
        Ux[(size_t)row * Hc + h] = m * (accu[r] + bu);
        W[(size_t)row * Hc + h] = m * m * (accv[r] + bv);
    }
}

// ---------------------------------------------------------------------------
// Kernel 2: stream edge_gate once. 2 i-rows per block so each L2-resident W
// load serves two eg streams. eg loads are non-temporal (zero reuse — keep
// the 268 MB stream out of L2/L3 so W/Ux stay hot).
// grid = 1024 blocks (rows 2*blk, 2*blk+1), block = 256:
//   c = tid&31 -> h/4 (float4 over H=128), g = tid>>5 -> j in {g, g+8, ...}
// 4 blocks/CU -> 16 waves/CU; unroll4 x 3 loads x 16B in flight per thread.
// ---------------------------------------------------------------------------
__global__ __launch_bounds__(256) void nf_edge(
    const float* __restrict__ eg,    // (B, N, N, H)
    const float* __restrict__ mask,  // (B, N)
    const float* __restrict__ Ux,    // (B, N, H)
    const float* __restrict__ W,     // (B, N, H)
    float* __restrict__ out)         // (B, N, H)
{
    __shared__ float red1[2][8][Hc];   // 8 KB
    __shared__ float red0[2][8][Hc];   // 8 KB
    __shared__ float mrow[Nc];         // 1 KB

    const int tid = threadIdx.x;
    const int c = tid & 31;    // h4 index
    const int g = tid >> 5;    // j group 0..7
    const int row0 = blockIdx.x * 2;   // b*Nc + i0 (i0 even, same b for both)
    const int b = row0 >> 8;

    mrow[tid] = mask[b * Nc + tid];    // tid == j
    __syncthreads();

    const f4* __restrict__ e0p =
        reinterpret_cast<const f4*>(eg + (size_t)row0 * Nc * Hc) + c;
    const f4* __restrict__ e1p =
        reinterpret_cast<const f4*>(eg + (size_t)(row0 + 1) * Nc * Hc) + c;
    const f4* __restrict__ wp =
        reinterpret_cast<const f4*>(W + (size_t)b * Nc * Hc) + c;

    f4 s1a = {0.f, 0.f, 0.f, 0.f};
    f4 s0a = {0.f, 0.f, 0.f, 0.f};
    f4 s1b = {0.f, 0.f, 0.f, 0.f};
    f4 s0b = {0.f, 0.f, 0.f, 0.f};

#pragma unroll 4
    for (int jj = 0; jj < Nc / 8; ++jj) {
        const int j = jj * 8 + g;
        const float mj = mrow[j];
        const f4 e0 = __builtin_nontemporal_load(e0p + (size_t)j * (Hc / 4));
        const f4 e1 = __builtin_nontemporal_load(e1p + (size_t)j * (Hc / 4));
        const f4 w  = wp[(size_t)j * (Hc / 4)];
        s1a += e0 * w;
        s0a += e0 * mj;
        s1b += e1 * w;
        s0b += e1 * mj;
    }

    *reinterpret_cast<f4*>(&red1[0][g][c * 4]) = s1a;
    *reinterpret_cast<f4*>(&red0[0][g][c * 4]) = s0a;
    *reinterpret_cast<f4*>(&red1[1][g][c * 4]) = s1b;
    *reinterpret_cast<f4*>(&red0[1][g][c * 4]) = s0b;
    __syncthreads();

    // 256 threads -> 2 rows x 128 h, one output each
    const int r = tid >> 7;         // 0..1
    const int h = tid & (Hc - 1);   // 0..127
    float a1 = 0.f, a0 = 0.f;
#pragma unroll
    for (int g2 = 0; g2 < 8; ++g2) {
        a1 += red1[r][g2][h];
        a0 += red0[r][g2][h];
    }
    const int row = row0 + r;
    const float mi = mrow[row & (Nc - 1)];
    const size_t oidx = (size_t)row * Hc + h;
    out[oidx] = Ux[oidx] + (mi * a1) / (EPSF + mi * a0);
}

extern "C" void kernel_launch(void* const* d_in, const int* in_sizes, int n_in,
                              void* d_out, int out_size, void* d_ws, size_t ws_size,
                              hipStream_t stream) {
    const float* x    = (const float*)d_in[0];  // (B,N,H)
    const float* eg   = (const float*)d_in[1];  // (B,N,N,H)
    const float* mask = (const float*)d_in[2];  // (B,N)
    const float* Uw   = (const float*)d_in[3];  // (H,H)
    const float* Ub   = (const float*)d_in[4];  // (H)
    const float* Vw   = (const float*)d_in[5];  // (H,H)
    const float* Vb   = (const float*)d_in[6];  // (H)
    float* out = (float*)d_out;

    // workspace: Ux (ROWS*H) then W (ROWS*H) floats = 2 MB total
    float* Ux = (float*)d_ws;
    float* W  = Ux + (size_t)ROWS * Hc;

    nf_prep<<<ROWS / 4, 128, 0, stream>>>(x, mask, Uw, Ub, Vw, Vb, Ux, W);
    nf_edge<<<ROWS / 2, 256, 0, stream>>>(eg, mask, Ux, W, out);
}

// Round 4
// 358.913 us; speedup vs baseline: 1.0749x; 1.0032x over previous
//
#include <hip/hip_runtime.h>

#define EPSF 1e-20f

// Problem shape (fixed): B=8, N=256, H=128
// edge_gate (B,N,N,H) fp32 = 268.4 MB -> the one unavoidable HBM stream.
// Kernel roofline: 268 MB / 6.3-6.7 TB/s ~= 40-43 us. Measured dur_us carries
// a ~310 us harness floor (d_ws 1 GiB re-poison @ ~160 us + input restores).

namespace {
constexpr int Bc = 8;
constexpr int Nc = 256;
constexpr int Hc = 128;
constexpr int ROWS = Bc * Nc;  // 2048
}

typedef float f4 __attribute__((ext_vector_type(4)));

// ---------------------------------------------------------------------------
// Kernel 1: per row (b,n):
//   Ux[row,h] = m * (sum_k x[row,k]*Uw[h,k] + Ub[h])
//   W [row,h] = m * m * (sum_k x[row,k]*Vw[h,k] + Vb[h])
// (W = mask_j * Vx: reference multiplies eg by mask_j and Vx already carries
//  one mask_j factor.)
// ---------------------------------------------------------------------------
__global__ __launch_bounds__(128) void nf_prep(
    const float* __restrict__ x,     // (ROWS, H)
    const float* __restrict__ mask,  // (ROWS)
    const float* __restrict__ Uw,    // (H, H)
    const float* __restrict__ Ub,    // (H)
    const float* __restrict__ Vw,    // (H, H)
    const float* __restrict__ Vb,    // (H)
    float* __restrict__ Ux,          // (ROWS, H) out
    float* __restrict__ W)           // (ROWS, H) out
{
    const int h = threadIdx.x;           // 0..127
    const int row0 = blockIdx.x * 4;     // 4 rows per block

    float accu[4] = {0.f, 0.f, 0.f, 0.f};
    float accv[4] = {0.f, 0.f, 0.f, 0.f};

    const float4* uw4 = reinterpret_cast<const float4*>(Uw + (size_t)h * Hc);
    const float4* vw4 = reinterpret_cast<const float4*>(Vw + (size_t)h * Hc);

    for (int k4 = 0; k4 < Hc / 4; ++k4) {
        const float4 u = uw4[k4];
        const float4 v = vw4[k4];
#pragma unroll
        for (int r = 0; r < 4; ++r) {
            // wave-uniform address -> scalar load path
            const float4 xv = *reinterpret_cast<const float4*>(
                x + (size_t)(row0 + r) * Hc + k4 * 4);
            accu[r] += xv.x * u.x + xv.y * u.y + xv.z * u.z + xv.w * u.w;
            accv[r] += xv.x * v.x + xv.y * v.y + xv.z * v.z + xv.w * v.w;
        }
    }

    const float bu = Ub[h];
    const float bv = Vb[h];
#pragma unroll
    for (int r = 0; r < 4; ++r) {
        const int row = row0 + r;
        const float m = mask[row];
        Ux[(size_t)row * Hc + h] = m * (accu[r] + bu);
        W[(size_t)row * Hc + h] = m * m * (accv[r] + bv);
    }
}

// ---------------------------------------------------------------------------
// Kernel 2: stream edge_gate once. 4 i-rows per block so each L2-resident W
// load serves four eg streams (VMEM instrs per eg-byte cut 2.4x vs 2-row).
// eg loads are non-temporal (zero reuse — keep the 268 MB stream out of
// L2/L3 so W/Ux stay hot).
// grid = 512 blocks (rows 4*blk .. 4*blk+3, same b), block = 256:
//   c = tid&31 -> h/4 (float4 over H=128), g = tid>>5 -> j in {g, g+8, ...}
// 2 blocks/CU -> 8 waves/CU; in-flight bytes >> latency-BW product.
// ---------------------------------------------------------------------------
__global__ __launch_bounds__(256) void nf_edge(
    const float* __restrict__ eg,    // (B, N, N, H)
    const float* __restrict__ mask,  // (B, N)
    const float* __restrict__ Ux,    // (B, N, H)
    const float* __restrict__ W,     // (B, N, H)
    float* __restrict__ out)         // (B, N, H)
{
    __shared__ float red1[4][8][Hc];   // 16 KB
    __shared__ float red0[4][8][Hc];   // 16 KB
    __shared__ float mrow[Nc];         // 1 KB

    const int tid = threadIdx.x;
    const int c = tid & 31;    // h4 index
    const int g = tid >> 5;    // j group 0..7
    const int row0 = blockIdx.x * 4;   // b*Nc + i0, all 4 rows same b
    const int b = row0 >> 8;

    mrow[tid] = mask[b * Nc + tid];    // tid == j
    __syncthreads();

    const f4* __restrict__ e0p =
        reinterpret_cast<const f4*>(eg + (size_t)row0 * Nc * Hc) + c;
    const f4* __restrict__ e1p = e0p + (size_t)Nc * (Hc / 4);
    const f4* __restrict__ e2p = e1p + (size_t)Nc * (Hc / 4);
    const f4* __restrict__ e3p = e2p + (size_t)Nc * (Hc / 4);
    const f4* __restrict__ wp =
        reinterpret_cast<const f4*>(W + (size_t)b * Nc * Hc) + c;

    f4 s1[4], s0[4];
#pragma unroll
    for (int r = 0; r < 4; ++r) {
        s1[r] = (f4){0.f, 0.f, 0.f, 0.f};
        s0[r] = (f4){0.f, 0.f, 0.f, 0.f};
    }

#pragma unroll 4
    for (int jj = 0; jj < Nc / 8; ++jj) {
        const int j = jj * 8 + g;
        const size_t joff = (size_t)j * (Hc / 4);
        const float mj = mrow[j];
        const f4 e0 = __builtin_nontemporal_load(e0p + joff);
        const f4 e1 = __builtin_nontemporal_load(e1p + joff);
        const f4 e2 = __builtin_nontemporal_load(e2p + joff);
        const f4 e3 = __builtin_nontemporal_load(e3p + joff);
        const f4 w  = wp[joff];
        s1[0] += e0 * w;  s0[0] += e0 * mj;
        s1[1] += e1 * w;  s0[1] += e1 * mj;
        s1[2] += e2 * w;  s0[2] += e2 * mj;
        s1[3] += e3 * w;  s0[3] += e3 * mj;
    }

#pragma unroll
    for (int r = 0; r < 4; ++r) {
        *reinterpret_cast<f4*>(&red1[r][g][c * 4]) = s1[r];
        *reinterpret_cast<f4*>(&red0[r][g][c * 4]) = s0[r];
    }
    __syncthreads();

    // 256 threads, 512 outputs -> 2 outputs/thread (rows r and r+2)
#pragma unroll
    for (int rr = 0; rr < 2; ++rr) {
        const int r = (tid >> 7) + rr * 2;     // 0..3
        const int h = tid & (Hc - 1);          // 0..127
        float a1 = 0.f, a0 = 0.f;
#pragma unroll
        for (int g2 = 0; g2 < 8; ++g2) {
            a1 += red1[r][g2][h];
            a0 += red0[r][g2][h];
        }
        const int row = row0 + r;
        const float mi = mrow[row & (Nc - 1)];
        const size_t oidx = (size_t)row * Hc + h;
        out[oidx] = Ux[oidx] + (mi * a1) / (EPSF + mi * a0);
    }
}

extern "C" void kernel_launch(void* const* d_in, const int* in_sizes, int n_in,
                              void* d_out, int out_size, void* d_ws, size_t ws_size,
                              hipStream_t stream) {
    const float* x    = (const float*)d_in[0];  // (B,N,H)
    const float* eg   = (const float*)d_in[1];  // (B,N,N,H)
    const float* mask = (const float*)d_in[2];  // (B,N)
    const float* Uw   = (const float*)d_in[3];  // (H,H)
    const float* Ub   = (const float*)d_in[4];  // (H)
    const float* Vw   = (const float*)d_in[5];  // (H,H)
    const float* Vb   = (const float*)d_in[6];  // (H)
    float* out = (float*)d_out;

    // workspace: Ux (ROWS*H) then W (ROWS*H) floats = 2 MB total
    float* Ux = (float*)d_ws;
    float* W  = Ux + (size_t)ROWS * Hc;

    nf_prep<<<ROWS / 4, 128, 0, stream>>>(x, mask, Uw, Ub, Vw, Vb, Ux, W);
    nf_edge<<<ROWS / 4, 256, 0, stream>>>(eg, mask, Ux, W, out);
}